// Round 7
// baseline (12763.702 us; speedup 1.0000x reference)
//
#include <hip/hip_runtime.h>
#include <math.h>

#define NB   32
#define TH   128
#define NL   6
#define DD   128
#define NH   4
#define DHD  32
#define TCAP 128
#define D3   384
#define D4   512

typedef _Float16 f16;
typedef _Float16 f16x2 __attribute__((ext_vector_type(2)));
typedef _Float16 f16x8 __attribute__((ext_vector_type(8)));

// ---- workspace layout (f16 units) ----
#define N_WQ (NL * D3 * DD)   // col-major [l][c][k<128], LN1-folded
#define N_WP (NL * DD * DD)   // [l][c][k<128]
#define N_WF (NL * D4 * DD)   // [l][c][k<128], LN2-folded
#define N_WG (NL * DD * D4)   // [l][c][k<512]
#define N_WH (DD)             // lnf-folded head column
#define NF16 (N_WQ + N_WP + N_WF + N_WG + N_WH)
// float2 S/T per column, ordered: qkv | proj | fc | fc2 | head
#define BQ 0
#define BP (NL * D3)
#define BF (BP + NL * DD)
#define BG (BF + NL * D4)
#define BH (BG + NL * DD)
#define NCOLS (BH + 1)
#define NCOLS_PAD 6914        // pad for 16B alignment of K cache

#define BAR_LDS() asm volatile("s_waitcnt lgkmcnt(0)\n\ts_barrier" ::: "memory")
#define BAR_ALL() asm volatile("s_waitcnt vmcnt(0) lgkmcnt(0)\n\ts_barrier" ::: "memory")
#define WAVE_LDS_WAIT() asm volatile("s_waitcnt lgkmcnt(0)" ::: "memory")

// ---- prep: fold LN into weights, transpose to column-major, compute S/T ----
__global__ void prep(const float* __restrict__ qkv_w, const float* __restrict__ qkv_b,
                     const float* __restrict__ proj_w, const float* __restrict__ proj_b,
                     const float* __restrict__ fc_w,  const float* __restrict__ fc_b,
                     const float* __restrict__ fc2_w, const float* __restrict__ fc2_b,
                     const float* __restrict__ ln1w, const float* __restrict__ ln1b,
                     const float* __restrict__ ln2w, const float* __restrict__ ln2b,
                     const float* __restrict__ lnfw, const float* __restrict__ lnfb,
                     const float* __restrict__ head_w, const float* __restrict__ head_b,
                     f16* __restrict__ wf, float* __restrict__ st) {
    int g = blockIdx.x * blockDim.x + threadIdx.x;
    if (g >= NCOLS) return;
    float S = 0.f, T = 0.f;
    if (g < BP) {                       // qkv col
        int l = g / D3, c = g % D3;
        f16* dst = wf + ((size_t)l * D3 + c) * DD;
        for (int k = 0; k < DD; k++) {
            float wv = qkv_w[((size_t)l * DD + k) * D3 + c];
            float wp = ln1w[l * DD + k] * wv;
            dst[k] = (f16)wp; S += wp; T += ln1b[l * DD + k] * wv;
        }
        T += qkv_b[l * D3 + c];
    } else if (g < BF) {                // proj col
        int g2 = g - BP, l = g2 / DD, c = g2 % DD;
        f16* dst = wf + N_WQ + ((size_t)l * DD + c) * DD;
        for (int k = 0; k < DD; k++)
            dst[k] = (f16)proj_w[((size_t)l * DD + k) * DD + c];
        T = proj_b[l * DD + c];
    } else if (g < BG) {                // fc col
        int g2 = g - BF, l = g2 / D4, c = g2 % D4;
        f16* dst = wf + N_WQ + N_WP + ((size_t)l * D4 + c) * DD;
        for (int k = 0; k < DD; k++) {
            float wv = fc_w[((size_t)l * DD + k) * D4 + c];
            float wp = ln2w[l * DD + k] * wv;
            dst[k] = (f16)wp; S += wp; T += ln2b[l * DD + k] * wv;
        }
        T += fc_b[l * D4 + c];
    } else if (g < BH) {                // fc2 col
        int g2 = g - BG, l = g2 / DD, c = g2 % DD;
        f16* dst = wf + N_WQ + N_WP + N_WF + ((size_t)l * DD + c) * D4;
        for (int k = 0; k < D4; k++)
            dst[k] = (f16)fc2_w[((size_t)l * D4 + k) * DD + c];
        T = fc2_b[l * DD + c];
    } else {                            // head col (lnf folded)
        f16* dst = wf + N_WQ + N_WP + N_WF + N_WG;
        for (int k = 0; k < DD; k++) {
            float wp = lnfw[k] * head_w[k];
            dst[k] = (f16)wp; S += wp; T += lnfb[k] * head_w[k];
        }
        T += head_b[0];
    }
    st[2 * g] = S; st[2 * g + 1] = T;
}

__device__ __forceinline__ float dotv(f16x8 a, f16x8 b, float acc) {
    acc = __builtin_amdgcn_fdot2((f16x2){a[0], a[1]}, (f16x2){b[0], b[1]}, acc, false);
    acc = __builtin_amdgcn_fdot2((f16x2){a[2], a[3]}, (f16x2){b[2], b[3]}, acc, false);
    acc = __builtin_amdgcn_fdot2((f16x2){a[4], a[5]}, (f16x2){b[4], b[5]}, acc, false);
    acc = __builtin_amdgcn_fdot2((f16x2){a[6], a[7]}, (f16x2){b[6], b[7]}, acc, false);
    return acc;
}
// full-K column dot: 16 chunks (K=128)
__device__ __forceinline__ float colK128(const f16x8* __restrict__ W, const f16x8* X) {
    float a0 = 0, a1 = 0, a2 = 0, a3 = 0;
    #pragma unroll
    for (int t = 0; t < 16; t += 4) {
        a0 = dotv(X[t],     W[t],     a0);
        a1 = dotv(X[t + 1], W[t + 1], a1);
        a2 = dotv(X[t + 2], W[t + 2], a2);
        a3 = dotv(X[t + 3], W[t + 3], a3);
    }
    return (a0 + a1) + (a2 + a3);
}
__device__ __forceinline__ void stats(const float* xf, int lane, float& rs, float& mneg) {
    float v0 = xf[lane], v1 = xf[lane + 64];
    float sm = v0 + v1, sq = v0 * v0 + v1 * v1;
    #pragma unroll
    for (int o = 1; o < 64; o <<= 1) { sm += __shfl_xor(sm, o); sq += __shfl_xor(sq, o); }
    float m = sm * (1.f / DD);
    rs = rsqrtf(sq * (1.f / DD) - m * m + 1e-5f);
    mneg = -rs * m;
}
__device__ __forceinline__ float gelu_tanh(float v) {
    float t = v * v * v;
    return 0.5f * v * (1.f + tanhf(0.7978845608028654f * (v + 0.044715f * t)));
}

__global__ __launch_bounds__(512) void gpt_loop(
    const float* __restrict__ data, const float* __restrict__ r,
    const float* __restrict__ wte_w, const float* __restrict__ wte_b,
    const float* __restrict__ wpe,
    const f16* __restrict__ wf, const float* __restrict__ st,
    f16* __restrict__ Kc, f16* __restrict__ Vtc,
    float* __restrict__ Y)
{
    const int b = blockIdx.x, tid = threadIdx.x;
    const int lane = tid & 63, wv = tid >> 6;

    const f16* WQ = wf;
    const f16* WP = WQ + N_WQ;
    const f16* WF = WP + N_WP;
    const f16* WG = WF + N_WF;
    const f16* WH = WG + N_WG;

    __shared__ float xf[DD];
    __shared__ __align__(16) f16 xh[DD], o16[DD], hm[D4], vcur[DD];
    __shared__ __align__(16) f16 qw[NH][DHD], kw[NH][DHD], p16[NH][TCAP];
    __shared__ float s_sh, u_sh;

    const float p0 = data[b * 2 + 0];
    const float p1 = data[b * 2 + 1];

    f16* Kb  = Kc  + (size_t)b * NL * TCAP * DD;   // [l][j][c]
    f16* Vtb = Vtc + (size_t)b * NL * DD * TCAP;   // [l][c][j]

    if (tid == 0) { s_sh = 0.f; u_sh = 0.f; }
    __syncthreads();
    if (tid < DD) {   // embed step 0 (s=u=0)
        float e = r[b * TH + 0];
        float xv = e * wte_w[tid] + wte_b[tid] + wpe[tid];
        xf[tid] = xv; xh[tid] = (f16)xv;
    }

    for (int i = 0; i < TH; i++) {
        for (int l = 0; l < NL; l++) {
            BAR_ALL();   // x visible; all global K/Vt stores drained

            // ---- Phase A: qkv (LN1 folded, col-per-thread) + in-wave scores ----
            if (tid < 384) {
                float rs, mneg; stats(xf, lane, rs, mneg);
                int col;
                if (wv < 4) col = (lane < 32) ? (wv * 32 + lane) : (DD + wv * 32 + (lane - 32));
                else        col = 2 * DD + (wv - 4) * 64 + lane;
                const f16x8* Wc = (const f16x8*)(WQ + ((size_t)l * D3 + col) * DD);
                float acc = colK128(Wc, (const f16x8*)xh);
                float Sc = st[2 * (l * D3 + col)], Tc = st[2 * (l * D3 + col) + 1];
                float out = rs * acc + mneg * Sc + Tc;
                if (wv < 4) {
                    if (lane < 32) qw[wv][lane] = (f16)out;
                    else { kw[wv][lane - 32] = (f16)out;
                           Kb[((size_t)l * TCAP + i) * DD + (col - DD)] = (f16)out; }
                } else {
                    int c = col - 2 * DD;
                    vcur[c] = (f16)out;
                    Vtb[((size_t)l * DD + c) * TCAP + i] = (f16)out;
                }
            }
            if (wv < NH) {   // scores + softmax, fully in-wave
                WAVE_LDS_WAIT();
                const int h = wv;
                const f16x8* qp = (const f16x8*)qw[h];
                f16x8 q8[4] = { qp[0], qp[1], qp[2], qp[3] };
                const int j0 = lane, j1 = lane + 64;
                float sc0 = -1e30f, sc1 = -1e30f;
                const float sscale = 0.17677669529663687f;
                if (j0 <= i) {
                    const f16x8* Kj = (j0 == i) ? (const f16x8*)kw[h]
                        : (const f16x8*)(Kb + ((size_t)l * TCAP + j0) * DD + h * DHD);
                    float d = 0.f;
                    #pragma unroll
                    for (int g = 0; g < 4; g++) d = dotv(q8[g], Kj[g], d);
                    sc0 = d * sscale;
                }
                if (j1 <= i) {
                    const f16x8* Kj = (j1 == i) ? (const f16x8*)kw[h]
                        : (const f16x8*)(Kb + ((size_t)l * TCAP + j1) * DD + h * DHD);
                    float d = 0.f;
                    #pragma unroll
                    for (int g = 0; g < 4; g++) d = dotv(q8[g], Kj[g], d);
                    sc1 = d * sscale;
                }
                float mx = fmaxf(sc0, sc1);
                #pragma unroll
                for (int o = 1; o < 64; o <<= 1) mx = fmaxf(mx, __shfl_xor(mx, o));
                float e0 = (j0 <= i) ? __expf(sc0 - mx) : 0.f;
                float e1 = (j1 <= i) ? __expf(sc1 - mx) : 0.f;
                float se = e0 + e1;
                #pragma unroll
                for (int o = 1; o < 64; o <<= 1) se += __shfl_xor(se, o);
                float inv = 1.f / se;
                p16[h][j0] = (f16)(e0 * inv);
                p16[h][j1] = (f16)(e1 * inv);
            }
            BAR_LDS();

            // ---- Phase B: AV (Vt cols contiguous; row i via vcur) ----
            if (wv < NH) {
                const int h = wv, c32 = lane & 31, jh = lane >> 5;
                const int cg = h * 32 + c32;
                const f16* vco = Vtb + ((size_t)l * DD + cg) * TCAP;
                float a = 0.f;
                const int jend = min(i, jh * 64 + 63);
                for (int j = jh * 64; j <= jend; j += 8) {
                    f16x8 vv = *(const f16x8*)(vco + j);
                    f16x8 pp = *(const f16x8*)(&p16[h][j]);
                    if ((unsigned)(i - j) < 8u) pp[i - j] = (f16)0;   // row i handled via vcur
                    a = dotv(pp, vv, a);
                }
                if ((i >> 6) == jh) a += (float)p16[h][i] * (float)vcur[cg];
                a += __shfl_xor(a, 32);
                if (lane < 32) o16[cg] = (f16)a;
            }
            BAR_LDS();

            // ---- Phase C: attn proj + residual (col-per-thread) ----
            if (tid < DD) {
                const f16x8* Wc = (const f16x8*)(WP + ((size_t)l * DD + tid) * DD);
                float acc = colK128(Wc, (const f16x8*)o16);
                float Tc = st[2 * (BP + l * DD + tid) + 1];
                float xv = xf[tid] + acc + Tc;
                xf[tid] = xv; xh[tid] = (f16)xv;
            }
            BAR_LDS();

            // ---- Phase D: fc (LN2 folded) + gelu, all 512 threads ----
            {
                float rs, mneg; stats(xf, lane, rs, mneg);
                const f16x8* Wc = (const f16x8*)(WF + ((size_t)l * D4 + tid) * DD);
                float acc = colK128(Wc, (const f16x8*)xh);
                float Sc = st[2 * (BF + l * D4 + tid)], Tc = st[2 * (BF + l * D4 + tid) + 1];
                hm[tid] = (f16)gelu_tanh(rs * acc + mneg * Sc + Tc);
            }
            BAR_LDS();

            // ---- Phase E: fc2 (2-way in-wave k-split) + residual ----
            if (tid < 256) {
                const int c = wv * 32 + (lane & 31), ks = lane >> 5;
                const f16x8* Wc = (const f16x8*)(WG + ((size_t)l * DD + c) * D4 + ks * 256);
                const f16x8* Hm = (const f16x8*)(hm + ks * 256);
                float a0 = 0, a1 = 0, a2 = 0, a3 = 0;
                #pragma unroll 8
                for (int t = 0; t < 32; t += 4) {
                    a0 = dotv(Hm[t],     Wc[t],     a0);
                    a1 = dotv(Hm[t + 1], Wc[t + 1], a1);
                    a2 = dotv(Hm[t + 2], Wc[t + 2], a2);
                    a3 = dotv(Hm[t + 3], Wc[t + 3], a3);
                }
                float acc = (a0 + a1) + (a2 + a3);
                acc += __shfl_xor(acc, 32);
                if (lane < 32) {
                    float Tc = st[2 * (BG + l * DD + c) + 1];
                    float xv = xf[c] + acc + Tc;
                    xf[c] = xv; xh[c] = (f16)xv;
                }
            }
        } // layers
        BAR_LDS();

        // ---- head (lnf folded) + state update, wave 0 ----
        if (wv == 0) {
            float rs, mneg; stats(xf, lane, rs, mneg);
            f16x2 xp = ((const f16x2*)xh)[lane];
            f16x2 wp = ((const f16x2*)WH)[lane];
            float d = __builtin_amdgcn_fdot2(xp, wp, 0.f, false);
            #pragma unroll
            for (int o = 1; o < 64; o <<= 1) d += __shfl_xor(d, o);
            if (lane == 0) {
                float Sc = st[2 * BH], Tc = st[2 * BH + 1];
                float u = rs * d + mneg * Sc + Tc;
                float s = s_sh;
                Y[b * TH + i] = s;
                s_sh = s + (-p0 * s + p1 * tanhf(u));
                u_sh = u;
            }
        }
        BAR_LDS();

        // ---- embed for step i+1 ----
        if (i + 1 < TH && tid < DD) {
            float e = r[b * TH + i + 1] - s_sh;
            float xv = e * wte_w[tid] + u_sh * wte_w[DD + tid] + wte_b[tid]
                     + wpe[(i + 1) * DD + tid];
            xf[tid] = xv; xh[tid] = (f16)xv;
        }
    } // steps
}

extern "C" void kernel_launch(void* const* d_in, const int* in_sizes, int n_in,
                              void* d_out, int out_size, void* d_ws, size_t ws_size,
                              hipStream_t stream) {
    const float* data   = (const float*)d_in[0];
    const float* r      = (const float*)d_in[1];
    const float* wte_w  = (const float*)d_in[2];
    const float* wte_b  = (const float*)d_in[3];
    const float* wpe    = (const float*)d_in[4];
    const float* ln1_w  = (const float*)d_in[5];
    const float* ln1_b  = (const float*)d_in[6];
    const float* ln2_w  = (const float*)d_in[7];
    const float* ln2_b  = (const float*)d_in[8];
    const float* qkv_w  = (const float*)d_in[9];
    const float* qkv_b  = (const float*)d_in[10];
    const float* proj_w = (const float*)d_in[11];
    const float* proj_b = (const float*)d_in[12];
    const float* fc_w   = (const float*)d_in[13];
    const float* fc_b   = (const float*)d_in[14];
    const float* fc2_w  = (const float*)d_in[15];
    const float* fc2_b  = (const float*)d_in[16];
    const float* lnf_w  = (const float*)d_in[17];
    const float* lnf_b  = (const float*)d_in[18];
    const float* head_w = (const float*)d_in[19];
    const float* head_b = (const float*)d_in[20];

    f16*   wfp = (f16*)d_ws;
    float* stp = (float*)(wfp + NF16);
    f16*   Kc  = (f16*)(stp + 2 * NCOLS_PAD);
    f16*   Vtc = Kc + (size_t)NB * NL * TCAP * DD;

    prep<<<(NCOLS + 255) / 256, 256, 0, stream>>>(
        qkv_w, qkv_b, proj_w, proj_b, fc_w, fc_b, fc2_w, fc2_b,
        ln1_w, ln1_b, ln2_w, ln2_b, lnf_w, lnf_b, head_w, head_b, wfp, stp);

    gpt_loop<<<NB, 512, 0, stream>>>(
        data, r, wte_w, wte_b, wpe, wfp, stp, Kc, Vtc, (float*)d_out);
}